// Round 8
// baseline (285.725 us; speedup 1.0000x reference)
//
#include <hip/hip_runtime.h>
#include <hip/hip_bf16.h>

typedef unsigned short u16;
typedef unsigned int   u32;
typedef unsigned long long u64;
typedef __attribute__((ext_vector_type(8))) short bf16x8;
typedef __attribute__((ext_vector_type(4))) float f32x4;
typedef __attribute__((ext_vector_type(16))) float f32x16;

#define MFMA16(a,b,c) __builtin_amdgcn_mfma_f32_16x16x32_bf16((a),(b),(c),0,0,0)
#define MFMA32(a,b,c) __builtin_amdgcn_mfma_f32_32x32x16_bf16((a),(b),(c),0,0,0)

#define GLD16(gp, lp) __builtin_amdgcn_global_load_lds( \
    (const __attribute__((address_space(1))) void*)(gp), \
    (__attribute__((address_space(3))) void*)(lp), 16, 0, 0)

__device__ inline u32 pkbf(float a, float b) {
  __hip_bfloat16 ha = __float2bfloat16(a), hb = __float2bfloat16(b);
  return (u32)(*(u16*)&ha) | ((u32)(*(u16*)&hb) << 16);
}
__device__ inline float b2f(u16 x) {
  __hip_bfloat16 h; *(u16*)&h = x; return __bfloat162float(h);
}
// fast bf16 pair pack: round (+0x8000) then byte-perm the two high halves
__device__ inline u32 pk2(float a, float b) {
  u32 ua = __builtin_bit_cast(u32, a) + 0x8000u;
  u32 ub = __builtin_bit_cast(u32, b) + 0x8000u;
  return __builtin_amdgcn_perm(ub, ua, 0x07060302u);
}
__device__ inline float fmax3(float a, float b, float c) {
  return fmaxf(fmaxf(a, b), c);
}

// ---------------------------------------------------------------- cast f32->bf16
__global__ __launch_bounds__(256) void cast_f32_bf16(const float* __restrict__ src,
                                                     u16* __restrict__ dst, int n4) {
  int i = blockIdx.x * 256 + threadIdx.x;
  if (i >= n4) return;
  float4 v = reinterpret_cast<const float4*>(src)[i];
  uint2 pk; pk.x = pkbf(v.x, v.y); pk.y = pkbf(v.z, v.w);
  reinterpret_cast<uint2*>(dst)[i] = pk;
}

// ---------------------------------------------------------------- big GEMM
// C = A * B^T. Tile 128x256, BK=32, 512 thr = 8 waves (2M x 4N). Counted
// vmcnt(3) + raw s_barrier pipeline (no vmcnt(0) drain in main loop).
__device__ inline void cstore(u16* C, size_t i, float v) {
  __hip_bfloat16 h = __float2bfloat16(v); C[i] = *(u16*)&h;
}
__device__ inline void cstore(float* C, size_t i, float v) { C[i] = v; }

template<typename OutT>
__global__ __launch_bounds__(512, 4) void gemm_big(const u16* __restrict__ A,
                                                   const u16* __restrict__ B,
                                                   OutT* __restrict__ C,
                                                   int M, int N, int K) {
  __shared__ u16 As[2][128 * 32];   // 16K
  __shared__ u16 Bs[2][256 * 32];   // 32K

  const int t = threadIdx.x;
  const int lane = t & 63, wid = t >> 6;
  const int l15 = lane & 15, l4 = lane >> 4;
  const int wr = wid >> 2, wc = wid & 3;

  const int nwg = gridDim.x * gridDim.y;
  int lid = blockIdx.y * gridDim.x + blockIdx.x;
  lid = (lid & 7) * (nwg >> 3) + (lid >> 3);
  const int m0 = (lid / gridDim.x) * 128, n0 = (lid % gridDim.x) * 256;

  const int ra = t >> 2;
  const int ca = (t & 3) ^ ((ra >> 1) & 3);
  const u16* Ag  = A + (size_t)(m0 + ra) * K + ca * 8;
  const u16* Bg0 = B + (size_t)(n0 + ra) * K + ca * 8;
  const u16* Bg1 = B + (size_t)(n0 + 128 + ra) * K + ca * 8;

#define STAGE(k0_, buf_) do {                                                 \
    GLD16(Ag  + (k0_), &As[buf_][t * 8]);                                     \
    GLD16(Bg0 + (k0_), &Bs[buf_][t * 8]);                                     \
    GLD16(Bg1 + (k0_), &Bs[buf_][4096 + t * 8]);                              \
  } while (0)

  const int nk = K >> 5;
  const int ks = (l15 >> 1) & 3;
  const int coff = ((l4 ^ ks) << 3);

  f32x4 acc[4][4] = {};

  STAGE(0, 0);
  STAGE(32, 1);

  for (int j = 0; j < nk; ++j) {
    const int cur = j & 1;
    if (j + 1 < nk) asm volatile("s_waitcnt vmcnt(3)" ::: "memory");
    else            asm volatile("s_waitcnt vmcnt(0)" ::: "memory");
    __builtin_amdgcn_s_barrier();
    __builtin_amdgcn_sched_barrier(0);

    bf16x8 af[4], bfr[4];
#pragma unroll
    for (int mi = 0; mi < 4; ++mi)
      af[mi] = *(const bf16x8*)&As[cur][(wr * 64 + mi * 16 + l15) * 32 + coff];
#pragma unroll
    for (int ni = 0; ni < 4; ++ni)
      bfr[ni] = *(const bf16x8*)&Bs[cur][(wc * 64 + ni * 16 + l15) * 32 + coff];
    __builtin_amdgcn_s_setprio(1);
#pragma unroll
    for (int mi = 0; mi < 4; ++mi)
#pragma unroll
      for (int ni = 0; ni < 4; ++ni)
        acc[mi][ni] = MFMA16(af[mi], bfr[ni], acc[mi][ni]);
    __builtin_amdgcn_s_setprio(0);

    __builtin_amdgcn_s_barrier();
    if (j + 2 < nk) STAGE((j + 2) << 5, cur);
  }

  const int crow = m0 + wr * 64 + (l4 << 2);
  const int ccol = n0 + wc * 64 + l15;
#pragma unroll
  for (int mi = 0; mi < 4; ++mi)
#pragma unroll
    for (int ni = 0; ni < 4; ++ni)
#pragma unroll
      for (int r = 0; r < 4; ++r)
        cstore(C, (size_t)(crow + mi * 16 + r) * N + (ccol + ni * 16), acc[mi][ni][r]);
#undef STAGE
}

// ---------------------------------------------------------------- RMSNorm + RoPE
// q heads pre-scaled by (1/sqrt(128))*log2(e) -> QK^T lands in exp2 domain.
__global__ __launch_bounds__(256) void rmsrope_kernel(u16* __restrict__ qkv) {
  const int t = threadIdx.x;
  const int lane = t & 63;
  const int gw = blockIdx.x * 4 + (t >> 6);
  const int row = gw / 20;
  const int hd = gw - row * 20;
  const int col = (hd < 16) ? hd * 128 : 2048 + (hd - 16) * 128;
  const size_t base = (size_t)row * 3072 + col;
  float x1 = b2f(qkv[base + lane]);
  float x2 = b2f(qkv[base + 64 + lane]);
  float ss = x1 * x1 + x2 * x2;
#pragma unroll
  for (int off = 32; off >= 1; off >>= 1) ss += __shfl_xor(ss, off, 64);
  const float qsc = (hd < 16) ? (0.08838834764831845f * 1.44269504088896340f)
                              : 1.0f;
  const float sc = rsqrtf(ss * (1.0f / 128.0f) + 1e-6f) * qsc;
  const int pos = row & 2047;
  const float inv_freq = exp2f(-(float)lane * (13.287712379549449f / 64.0f));
  float sn, cs;
  sincosf((float)pos * inv_freq, &sn, &cs);
  const float a = x1 * sc, b2 = x2 * sc;
  __hip_bfloat16 o1 = __float2bfloat16(a * cs - b2 * sn);
  __hip_bfloat16 o2 = __float2bfloat16(a * sn + b2 * cs);
  qkv[base + lane] = *(u16*)&o1;
  qkv[base + 64 + lane] = *(u16*)&o2;
}

// ---------------------------------------------------------------- V transpose
// vt[g=b*4+kvh][d=128][s=2048], sigma-permuted s within each 64-group.
__global__ __launch_bounds__(256) void vtrans_kernel(const u16* __restrict__ qkv,
                                                     u16* __restrict__ vt) {
  __shared__ u16 Ls[64 * 130];
  const int t = threadIdx.x;
  const int g = blockIdx.x & 7, sb = blockIdx.x >> 3;
  const int b = g >> 2, kvh = g & 3;
  const int vcol = 2560 + kvh * 128;
  {
    const int row = t >> 4, dch = t & 15;
    const u16* src = qkv + (size_t)(b * 2048 + sb * 64 + row) * 3072 + vcol + dch * 8;
#pragma unroll
    for (int it = 0; it < 4; ++it) {
      bf16x8 v = *(const bf16x8*)(src + (size_t)it * 16 * 3072);
      *(bf16x8*)&Ls[(row + it * 16) * 130 + dch * 8] = v;
    }
  }
  __syncthreads();
  const int c = t & 7, d0 = t >> 3;
  const int k0 = 4 * (8 * (c >> 2) + 4 * ((c >> 1) & 1) + (c & 1));
#pragma unroll
  for (int it = 0; it < 4; ++it) {
    const int d = d0 + 32 * it;
    u16 v[8];
#pragma unroll
    for (int e = 0; e < 8; ++e)
      v[e] = Ls[(k0 + (e & 3) + 8 * (e >> 2)) * 130 + d];
    u64 lo = (u64)v[0] | ((u64)v[1] << 16) | ((u64)v[2] << 32) | ((u64)v[3] << 48);
    u64 hi = (u64)v[4] | ((u64)v[5] << 16) | ((u64)v[6] << 32) | ((u64)v[7] << 48);
    u64* dst = (u64*)(vt + ((size_t)g * 128 + d) * 2048 + sb * 64 + c * 8);
    dst[0] = lo; dst[1] = hi;
  }
}

// ---------------------------------------------------------------- flash attention
// 256 blocks x 512 thr = 8 waves (4 qg x 2 k-halves). Block = (g, h, J),
// processes q128-tile pair (J, 15-J) sequentially: 34 KV64 iters (perfect
// balance). 2 blocks/CU x 8 waves = 16 waves/CU (4/SIMD) for latency hiding.
// Per-wave online (m,l,O) on its 32-k half; in-LDS k-half merge per phase.
// Swapped QK^T (exp2-domain), zero-shuffle PV via sigma-ordered vt, K/V
// staged with global_load_lds (XOR-swizzled), double-buffered, 1 barrier/iter.
__global__ __launch_bounds__(512, 4) void attn_kernel(const u16* __restrict__ qkv,
                                                      const u16* __restrict__ vt,
                                                      u16* __restrict__ ao) {
  __shared__ u16 SM[33280];         // [0..16K) Ks dbuf | [16K..32K) Vt dbuf | Mlb
#define KS(buf) (&SM[(buf) * 8192])
#define VT(buf) (&SM[16384 + (buf) * 8192])

  const int t = threadIdx.x;
  const int lane = t & 63, w = t >> 6;
  const int l31 = lane & 31, hi = lane >> 5;
  const int qg = w >> 1, hi2 = w & 1;

  const int bid = blockIdx.x;
  const int g = bid & 7;                  // XCD group = (b, kvh)
  const int b = g >> 2, kvh = g & 3;
  const int idx = bid >> 3;
  const int h = kvh * 4 + (idx & 3);
  const int J = idx >> 2;                 // 0..7 -> pair (J, 15-J) of q128 tiles

  const int kcol = 2048 + kvh * 128;
  const u16* vtg = vt + (size_t)g * 128 * 2048;

  const int krow_s = t >> 4, kchk = t & 15;   // K staging (2 GLD/thread)
  const int vd = t >> 3, vc = t & 7;          // V staging (2 GLD/thread)

#define STAGE_K(kb_, buf_) do {                                               \
    const size_t rb_ = (size_t)(b * 2048 + (kb_) * 64);                       \
    _Pragma("unroll")                                                         \
    for (int j_ = 0; j_ < 2; ++j_) {                                          \
      const int row_ = j_ * 32 + krow_s;                                      \
      GLD16(qkv + (rb_ + row_) * 3072 + kcol + ((kchk ^ (row_ & 7)) << 3),    \
            KS(buf_) + ((j_ * 512 + t) << 3));                                \
    } } while (0)

#define STAGE_V(kb_, buf_) do {                                               \
    _Pragma("unroll")                                                         \
    for (int j_ = 0; j_ < 2; ++j_) {                                          \
      const int d_ = j_ * 64 + vd;                                            \
      GLD16(vtg + (size_t)d_ * 2048 + (kb_) * 64 + ((vc ^ (d_ & 7)) << 3),    \
            VT(buf_) + ((j_ * 512 + t) << 3));                                \
    } } while (0)

  for (int ph = 0; ph < 2; ++ph) {
    const int qt = ph ? (15 - J) : J;
    const int q0 = qt * 128;
    const int nt = 2 * qt + 2;
    const int qrow = q0 + qg * 32 + l31;

    // Q fragments (B operand): col=q, k = st*16 + hi*8 + e (pre-scaled)
    bf16x8 qf[8];
    {
      const u16* qp = qkv + (size_t)(b * 2048 + qrow) * 3072 + h * 128 + hi * 8;
#pragma unroll
      for (int st = 0; st < 8; ++st) qf[st] = *(const bf16x8*)(qp + st * 16);
    }

    f32x16 o[4];
#pragma unroll
    for (int dt = 0; dt < 4; ++dt)
#pragma unroll
      for (int i = 0; i < 16; ++i) o[dt][i] = 0.f;
    float m2 = -1e30f, l = 0.f;

    STAGE_K(0, 0);
    STAGE_V(0, 0);

    for (int kb = 0; kb < nt; ++kb) {
      const int cur = kb & 1;
      __syncthreads();               // staging for [cur] drained; prior reads done
      const bool have_next = (kb + 1 < nt);
      if (have_next) {
        STAGE_K(kb + 1, cur ^ 1);    // GLD-only prefetch, lands during compute
        STAGE_V(kb + 1, cur ^ 1);
      }

      // ---- S^T = K_half Q^T  (rows k of this wave's 32-half, cols q)
      f32x16 s;
#pragma unroll
      for (int i = 0; i < 16; ++i) s[i] = 0.f;
      const int kbase = (32 * hi2 + l31) * 128;
      const int ksw = l31 & 7;
      __builtin_amdgcn_s_setprio(1);
#pragma unroll
      for (int st = 0; st < 8; ++st) {
        bf16x8 ka = *(const bf16x8*)&KS(cur)[kbase + (((2 * st + hi) ^ ksw) << 3)];
        s = MFMA32(ka, qf[st], s);
      }
      __builtin_amdgcn_s_setprio(0);

      // ---- mask (diag only), max3-tree row max
      const bool nomask = (kb * 64 + 32 * hi2 + 31) <= (q0 + qg * 32);
      if (!nomask) {
#pragma unroll
        for (int i = 0; i < 16; ++i) {
          const int kr = kb * 64 + 32 * hi2 + (i & 3) + 8 * (i >> 2) + 4 * hi;
          s[i] = (kr <= qrow) ? s[i] : -INFINITY;
        }
      }
      float a0 = fmax3(s[0], s[1], s[2]);
      float a1 = fmax3(s[3], s[4], s[5]);
      float a2 = fmax3(s[6], s[7], s[8]);
      float a3 = fmax3(s[9], s[10], s[11]);
      float a4 = fmax3(s[12], s[13], s[14]);
      float b0 = fmax3(a0, a1, s[15]);
      float b1 = fmax3(a2, a3, a4);
      float pm = fmaxf(b0, b1);
      pm = fmaxf(pm, __shfl_xor(pm, 32));
      // ---- defer-max rescale
      if (!__all(pm <= m2 + 8.f)) {
        const float m2n = fmaxf(m2, pm);
        const float fc = exp2f(m2 - m2n);
        m2 = m2n; l *= fc;
#pragma unroll
        for (int dt = 0; dt < 4; ++dt)
#pragma unroll
          for (int i = 0; i < 16; ++i) o[dt][i] *= fc;
      }
      // ---- P = exp2(z - m2), tree local sum (cross-hi deferred)
#pragma unroll
      for (int i = 0; i < 16; ++i) s[i] = exp2f(s[i] - m2);
      float t8[8];
#pragma unroll
      for (int i = 0; i < 8; ++i) t8[i] = s[i] + s[i + 8];
#pragma unroll
      for (int i = 0; i < 4; ++i) t8[i] = t8[i] + t8[i + 4];
      l += (t8[0] + t8[1]) + (t8[2] + t8[3]);
      // ---- P C-regs -> B-operand directly (sigma order, perm pack)
      union PB { u32 wd[4]; bf16x8 v; } p0u, p1u;
#pragma unroll
      for (int q_ = 0; q_ < 4; ++q_) {
        p0u.wd[q_] = pk2(s[2 * q_],     s[2 * q_ + 1]);
        p1u.wd[q_] = pk2(s[8 + 2 * q_], s[8 + 2 * q_ + 1]);
      }
      // ---- O^T += V^T_half P_half  (rows d, cols q)
      __builtin_amdgcn_s_setprio(1);
#pragma unroll
      for (int dt = 0; dt < 4; ++dt) {
        const int vrow = (dt * 32 + l31) * 64;
        const int dsw = l31 & 7;
        bf16x8 va0 = *(const bf16x8*)&VT(cur)[vrow + (((4 * hi2 + hi) ^ dsw) << 3)];
        o[dt] = MFMA32(va0, p0u.v, o[dt]);
        bf16x8 va1 = *(const bf16x8*)&VT(cur)[vrow + (((4 * hi2 + 2 + hi) ^ dsw) << 3)];
        o[dt] = MFMA32(va1, p1u.v, o[dt]);
      }
      __builtin_amdgcn_s_setprio(0);
    }

    // ---- in-block merge of the two k-halves (per q-group)
    __syncthreads();                 // all compute done; SM reusable
    const float l_tot = l + __shfl_xor(l, 32);
    float* Mrg = (float*)SM;         // 16K floats: [qg][dt][q=l31][32], XOR sw
    float* Mlb = (float*)&SM[32768]; // [qg][{m:0,l:32}+q]
    const int sw8 = l31 & 7;
    if (hi2) {
#pragma unroll
      for (int dt = 0; dt < 4; ++dt) {
        const int rbase = ((qg * 4 + dt) * 32 + l31) * 32;
#pragma unroll
        for (int m_ = 0; m_ < 4; ++m_) {
          f32x4 cv;
          cv[0] = o[dt][4 * m_ + 0]; cv[1] = o[dt][4 * m_ + 1];
          cv[2] = o[dt][4 * m_ + 2]; cv[3] = o[dt][4 * m_ + 3];
          *(f32x4*)&Mrg[rbase + (((hi * 4 + m_) ^ sw8) << 2)] = cv;
        }
      }
      if (hi == 0) {
        Mlb[qg * 64 + l31] = m2;
        Mlb[qg * 64 + 32 + l31] = l_tot;
      }
    }
    __syncthreads();
    if (!hi2) {
      const float m1 = Mlb[qg * 64 + l31];
      const float l1 = Mlb[qg * 64 + 32 + l31];
      const float ms = fmaxf(m2, m1);
      const float w0 = exp2f(m2 - ms), w1 = exp2f(m1 - ms);
      const float inv = 1.f / (w0 * l_tot + w1 * l1);
      const float aw0 = w0 * inv, aw1 = w1 * inv;
      const size_t orow = (size_t)(b * 2048 + qrow) * 2048 + h * 128;
#pragma unroll
      for (int dt = 0; dt < 4; ++dt) {
        const int rbase = ((qg * 4 + dt) * 32 + l31) * 32;
#pragma unroll
        for (int m_ = 0; m_ < 4; ++m_) {
          f32x4 o1v = *(const f32x4*)&Mrg[rbase + (((hi * 4 + m_) ^ sw8) << 2)];
          u64 val = 0;
#pragma unroll
          for (int r = 0; r < 4; ++r) {
            __hip_bfloat16 hb =
                __float2bfloat16(aw0 * o[dt][4 * m_ + r] + aw1 * o1v[r]);
            val |= (u64)(*(u16*)&hb) << (16 * r);
          }
          *(u64*)&ao[orow + dt * 32 + 8 * m_ + 4 * hi] = val;
        }
      }
    }
    __syncthreads();                 // protect Mrg/Mlb before next-phase staging
  }
#undef STAGE_K
#undef STAGE_V
#undef KS
#undef VT
}

// ---------------------------------------------------------------- launch
extern "C" void kernel_launch(void* const* d_in, const int* in_sizes, int n_in,
                              void* d_out, int out_size, void* d_ws, size_t ws_size,
                              hipStream_t stream) {
  const float* x  = (const float*)d_in[0];
  const float* wq = (const float*)d_in[2];
  const float* wk = (const float*)d_in[3];
  const float* wv = (const float*)d_in[4];
  const float* wo = (const float*)d_in[5];
  float* out = (float*)d_out;

  u16* xb   = (u16*)d_ws;                       // x bf16   [4096][2048]
  u16* wqkv = xb + (size_t)8388608;             // W bf16   [3072][2048]
  u16* qkv  = wqkv + (size_t)6291456;           // qkv      [4096][3072]
  u16* vtg  = qkv + (size_t)12582912;           // V^T      [8][128][2048]
  u16* ao   = xb;                               // attn out [4096][2048] (reuse xb)
  u16* wob  = wqkv;                             // wo bf16  [2048][2048] (reuse)

  cast_f32_bf16<<<8192, 256, 0, stream>>>(x,  xb,   2097152);
  cast_f32_bf16<<<4096, 256, 0, stream>>>(wq, wqkv, 1048576);
  cast_f32_bf16<<<1024, 256, 0, stream>>>(wk, wqkv + (size_t)4194304, 262144);
  cast_f32_bf16<<<1024, 256, 0, stream>>>(wv, wqkv + (size_t)5242880, 262144);

  gemm_big<u16><<<dim3(12, 32), 512, 0, stream>>>(xb, wqkv, qkv, 4096, 3072, 2048);

  cast_f32_bf16<<<4096, 256, 0, stream>>>(wo, wob, 1048576);

  rmsrope_kernel<<<20480, 256, 0, stream>>>(qkv);
  vtrans_kernel<<<256, 256, 0, stream>>>(qkv, vtg);

  attn_kernel<<<256, 512, 0, stream>>>(qkv, vtg, ao);

  gemm_big<float><<<dim3(8, 32), 512, 0, stream>>>(ao, wob, out, 4096, 2048, 2048);
}

// Round 9
// 229.615 us; speedup vs baseline: 1.2444x; 1.2444x over previous
//
#include <hip/hip_runtime.h>
#include <hip/hip_bf16.h>

typedef unsigned short u16;
typedef unsigned int   u32;
typedef unsigned long long u64;
typedef __attribute__((ext_vector_type(8))) short bf16x8;
typedef __attribute__((ext_vector_type(4))) float f32x4;
typedef __attribute__((ext_vector_type(16))) float f32x16;

#define MFMA16(a,b,c) __builtin_amdgcn_mfma_f32_16x16x32_bf16((a),(b),(c),0,0,0)
#define MFMA32(a,b,c) __builtin_amdgcn_mfma_f32_32x32x16_bf16((a),(b),(c),0,0,0)

#define GLD16(gp, lp) __builtin_amdgcn_global_load_lds( \
    (const __attribute__((address_space(1))) void*)(gp), \
    (__attribute__((address_space(3))) void*)(lp), 16, 0, 0)

__device__ inline u32 pkbf(float a, float b) {
  __hip_bfloat16 ha = __float2bfloat16(a), hb = __float2bfloat16(b);
  return (u32)(*(u16*)&ha) | ((u32)(*(u16*)&hb) << 16);
}
__device__ inline float b2f(u16 x) {
  __hip_bfloat16 h; *(u16*)&h = x; return __bfloat162float(h);
}
// fast bf16 pair pack: round (+0x8000) then byte-perm the two high halves
__device__ inline u32 pk2(float a, float b) {
  u32 ua = __builtin_bit_cast(u32, a) + 0x8000u;
  u32 ub = __builtin_bit_cast(u32, b) + 0x8000u;
  return __builtin_amdgcn_perm(ub, ua, 0x07060302u);
}
__device__ inline float fmax3(float a, float b, float c) {
  return fmaxf(fmaxf(a, b), c);
}

// ---------------------------------------------------------------- cast f32->bf16
__global__ __launch_bounds__(256) void cast_f32_bf16(const float* __restrict__ src,
                                                     u16* __restrict__ dst, int n4) {
  int i = blockIdx.x * 256 + threadIdx.x;
  if (i >= n4) return;
  float4 v = reinterpret_cast<const float4*>(src)[i];
  uint2 pk; pk.x = pkbf(v.x, v.y); pk.y = pkbf(v.z, v.w);
  reinterpret_cast<uint2*>(dst)[i] = pk;
}

// ---------------------------------------------------------------- big GEMM
// C = A * B^T. Tile 128x256, BK=32, 512 thr = 8 waves (2M x 4N). Counted
// vmcnt(3) + raw s_barrier pipeline (no vmcnt(0) drain in main loop).
__device__ inline void cstore(u16* C, size_t i, float v) {
  __hip_bfloat16 h = __float2bfloat16(v); C[i] = *(u16*)&h;
}
__device__ inline void cstore(float* C, size_t i, float v) { C[i] = v; }

template<typename OutT>
__global__ __launch_bounds__(512, 4) void gemm_big(const u16* __restrict__ A,
                                                   const u16* __restrict__ B,
                                                   OutT* __restrict__ C,
                                                   int M, int N, int K) {
  __shared__ u16 As[2][128 * 32];   // 16K
  __shared__ u16 Bs[2][256 * 32];   // 32K

  const int t = threadIdx.x;
  const int lane = t & 63, wid = t >> 6;
  const int l15 = lane & 15, l4 = lane >> 4;
  const int wr = wid >> 2, wc = wid & 3;

  const int nwg = gridDim.x * gridDim.y;
  int lid = blockIdx.y * gridDim.x + blockIdx.x;
  lid = (lid & 7) * (nwg >> 3) + (lid >> 3);
  const int m0 = (lid / gridDim.x) * 128, n0 = (lid % gridDim.x) * 256;

  const int ra = t >> 2;
  const int ca = (t & 3) ^ ((ra >> 1) & 3);
  const u16* Ag  = A + (size_t)(m0 + ra) * K + ca * 8;
  const u16* Bg0 = B + (size_t)(n0 + ra) * K + ca * 8;
  const u16* Bg1 = B + (size_t)(n0 + 128 + ra) * K + ca * 8;

#define STAGE(k0_, buf_) do {                                                 \
    GLD16(Ag  + (k0_), &As[buf_][t * 8]);                                     \
    GLD16(Bg0 + (k0_), &Bs[buf_][t * 8]);                                     \
    GLD16(Bg1 + (k0_), &Bs[buf_][4096 + t * 8]);                              \
  } while (0)

  const int nk = K >> 5;
  const int ks = (l15 >> 1) & 3;
  const int coff = ((l4 ^ ks) << 3);

  f32x4 acc[4][4] = {};

  STAGE(0, 0);
  STAGE(32, 1);

  for (int j = 0; j < nk; ++j) {
    const int cur = j & 1;
    if (j + 1 < nk) asm volatile("s_waitcnt vmcnt(3)" ::: "memory");
    else            asm volatile("s_waitcnt vmcnt(0)" ::: "memory");
    __builtin_amdgcn_s_barrier();
    __builtin_amdgcn_sched_barrier(0);

    bf16x8 af[4], bfr[4];
#pragma unroll
    for (int mi = 0; mi < 4; ++mi)
      af[mi] = *(const bf16x8*)&As[cur][(wr * 64 + mi * 16 + l15) * 32 + coff];
#pragma unroll
    for (int ni = 0; ni < 4; ++ni)
      bfr[ni] = *(const bf16x8*)&Bs[cur][(wc * 64 + ni * 16 + l15) * 32 + coff];
    __builtin_amdgcn_s_setprio(1);
#pragma unroll
    for (int mi = 0; mi < 4; ++mi)
#pragma unroll
      for (int ni = 0; ni < 4; ++ni)
        acc[mi][ni] = MFMA16(af[mi], bfr[ni], acc[mi][ni]);
    __builtin_amdgcn_s_setprio(0);

    __builtin_amdgcn_s_barrier();
    if (j + 2 < nk) STAGE((j + 2) << 5, cur);
  }

  const int crow = m0 + wr * 64 + (l4 << 2);
  const int ccol = n0 + wc * 64 + l15;
#pragma unroll
  for (int mi = 0; mi < 4; ++mi)
#pragma unroll
    for (int ni = 0; ni < 4; ++ni)
#pragma unroll
      for (int r = 0; r < 4; ++r)
        cstore(C, (size_t)(crow + mi * 16 + r) * N + (ccol + ni * 16), acc[mi][ni][r]);
#undef STAGE
}

// ---------------------------------------------------------------- RMSNorm + RoPE
// q heads pre-scaled by (1/sqrt(128))*log2(e) -> QK^T lands in exp2 domain.
__global__ __launch_bounds__(256) void rmsrope_kernel(u16* __restrict__ qkv) {
  const int t = threadIdx.x;
  const int lane = t & 63;
  const int gw = blockIdx.x * 4 + (t >> 6);
  const int row = gw / 20;
  const int hd = gw - row * 20;
  const int col = (hd < 16) ? hd * 128 : 2048 + (hd - 16) * 128;
  const size_t base = (size_t)row * 3072 + col;
  float x1 = b2f(qkv[base + lane]);
  float x2 = b2f(qkv[base + 64 + lane]);
  float ss = x1 * x1 + x2 * x2;
#pragma unroll
  for (int off = 32; off >= 1; off >>= 1) ss += __shfl_xor(ss, off, 64);
  const float qsc = (hd < 16) ? (0.08838834764831845f * 1.44269504088896340f)
                              : 1.0f;
  const float sc = rsqrtf(ss * (1.0f / 128.0f) + 1e-6f) * qsc;
  const int pos = row & 2047;
  const float inv_freq = exp2f(-(float)lane * (13.287712379549449f / 64.0f));
  float sn, cs;
  sincosf((float)pos * inv_freq, &sn, &cs);
  const float a = x1 * sc, b2 = x2 * sc;
  __hip_bfloat16 o1 = __float2bfloat16(a * cs - b2 * sn);
  __hip_bfloat16 o2 = __float2bfloat16(a * sn + b2 * cs);
  qkv[base + lane] = *(u16*)&o1;
  qkv[base + 64 + lane] = *(u16*)&o2;
}

// ---------------------------------------------------------------- V transpose
// vt[g=b*4+kvh][d=128][s=2048], sigma-permuted s within each 64-group.
__global__ __launch_bounds__(256) void vtrans_kernel(const u16* __restrict__ qkv,
                                                     u16* __restrict__ vt) {
  __shared__ u16 Ls[64 * 130];
  const int t = threadIdx.x;
  const int g = blockIdx.x & 7, sb = blockIdx.x >> 3;
  const int b = g >> 2, kvh = g & 3;
  const int vcol = 2560 + kvh * 128;
  {
    const int row = t >> 4, dch = t & 15;
    const u16* src = qkv + (size_t)(b * 2048 + sb * 64 + row) * 3072 + vcol + dch * 8;
#pragma unroll
    for (int it = 0; it < 4; ++it) {
      bf16x8 v = *(const bf16x8*)(src + (size_t)it * 16 * 3072);
      *(bf16x8*)&Ls[(row + it * 16) * 130 + dch * 8] = v;
    }
  }
  __syncthreads();
  const int c = t & 7, d0 = t >> 3;
  const int k0 = 4 * (8 * (c >> 2) + 4 * ((c >> 1) & 1) + (c & 1));
#pragma unroll
  for (int it = 0; it < 4; ++it) {
    const int d = d0 + 32 * it;
    u16 v[8];
#pragma unroll
    for (int e = 0; e < 8; ++e)
      v[e] = Ls[(k0 + (e & 3) + 8 * (e >> 2)) * 130 + d];
    u64 lo = (u64)v[0] | ((u64)v[1] << 16) | ((u64)v[2] << 32) | ((u64)v[3] << 48);
    u64 hi = (u64)v[4] | ((u64)v[5] << 16) | ((u64)v[6] << 32) | ((u64)v[7] << 48);
    u64* dst = (u64*)(vt + ((size_t)g * 128 + d) * 2048 + sb * 64 + c * 8);
    dst[0] = lo; dst[1] = hi;
  }
}

// ---------------------------------------------------------------- flash attention
// 512 blocks x 512 thr = 8 waves. Block = (g, h, j): q64-tile pair (31-j, j)
// processed CONCURRENTLY: waves 0-3 own tile 31-j, waves 4-7 own tile j (each
// tile: 2 qg x 2 k-halves). Both tiles consume the SAME KV stream kb=0,1,..
// so one shared staging serves 8 waves; short-tile waves go inactive past
// kb>j (barriers uniform). Loop nt = 32-j (17..32, mean 24.5). 2 blocks/CU x
// 8 waves = 16 waves/CU (4/SIMD). Per-wave online (m,l,O); in-LDS k-half
// merge at end. Swapped QK^T (exp2-domain), zero-shuffle PV via sigma-ordered
// vt, K/V via global_load_lds (XOR-swizzled), double-buffered, 1 barrier/iter.
__global__ __launch_bounds__(512, 2) void attn_kernel(const u16* __restrict__ qkv,
                                                      const u16* __restrict__ vt,
                                                      u16* __restrict__ ao) {
  __shared__ u16 SM[33280];         // Ks dbuf 16K | Vt dbuf 16K | (merge 65K)
#define KS(buf) (&SM[(buf) * 8192])
#define VT(buf) (&SM[16384 + (buf) * 8192])

  const int t = threadIdx.x;
  const int lane = t & 63, w = t >> 6;
  const int l31 = lane & 31, hi = lane >> 5;
  const int qg = (w >> 1) & 1, hi2 = w & 1;

  const int bid = blockIdx.x;
  const int g = bid & 7;                  // XCD group = (b, kvh)
  const int b = g >> 2, kvh = g & 3;
  const int idx = bid >> 3;
  const int h = kvh * 4 + (idx & 3);
  const int j = idx >> 2;                 // 0..15

  const int qt = (w < 4) ? (31 - j) : j;  // this wave's q64 tile
  const int nt = 32 - j;                  // loop length = long tile's KV count
  const int q0 = qt * 64;
  const int qrow = q0 + qg * 32 + l31;

  const int kcol = 2048 + kvh * 128;
  const u16* vtg = vt + (size_t)g * 128 * 2048;

  const int krow_s = t >> 4, kchk = t & 15;   // K staging (2 GLD/thread)
  const int vd = t >> 3, vc = t & 7;          // V staging (2 GLD/thread)

#define STAGE_K(kb_, buf_) do {                                               \
    const size_t rb_ = (size_t)(b * 2048 + (kb_) * 64);                       \
    _Pragma("unroll")                                                         \
    for (int j_ = 0; j_ < 2; ++j_) {                                          \
      const int row_ = j_ * 32 + krow_s;                                      \
      GLD16(qkv + (rb_ + row_) * 3072 + kcol + ((kchk ^ (row_ & 7)) << 3),    \
            KS(buf_) + ((j_ * 512 + t) << 3));                                \
    } } while (0)

#define STAGE_V(kb_, buf_) do {                                               \
    _Pragma("unroll")                                                         \
    for (int j_ = 0; j_ < 2; ++j_) {                                          \
      const int d_ = j_ * 64 + vd;                                            \
      GLD16(vtg + (size_t)d_ * 2048 + (kb_) * 64 + ((vc ^ (d_ & 7)) << 3),    \
            VT(buf_) + ((j_ * 512 + t) << 3));                                \
    } } while (0)

  // Q fragments (B operand): col=q, k = st*16 + hi*8 + e (pre-scaled)
  bf16x8 qf[8];
  {
    const u16* qp = qkv + (size_t)(b * 2048 + qrow) * 3072 + h * 128 + hi * 8;
#pragma unroll
    for (int st = 0; st < 8; ++st) qf[st] = *(const bf16x8*)(qp + st * 16);
  }

  f32x16 o[4];
#pragma unroll
  for (int dt = 0; dt < 4; ++dt)
#pragma unroll
    for (int i = 0; i < 16; ++i) o[dt][i] = 0.f;
  float m2 = -1e30f, l = 0.f;

  STAGE_K(0, 0);
  STAGE_V(0, 0);

  for (int kb = 0; kb < nt; ++kb) {
    const int cur = kb & 1;
    __syncthreads();               // staging for [cur] drained; prior reads done
    const bool have_next = (kb + 1 < nt);
    if (have_next) {
      STAGE_K(kb + 1, cur ^ 1);    // GLD-only prefetch, lands during compute
      STAGE_V(kb + 1, cur ^ 1);
    }
    const bool active = (kb <= qt);
    if (active) {
      // ---- S^T = K_half Q^T  (rows k of this wave's 32-half, cols q)
      f32x16 s;
#pragma unroll
      for (int i = 0; i < 16; ++i) s[i] = 0.f;
      const int kbase = (32 * hi2 + l31) * 128;
      const int ksw = l31 & 7;
      __builtin_amdgcn_s_setprio(1);
#pragma unroll
      for (int st = 0; st < 8; ++st) {
        bf16x8 ka = *(const bf16x8*)&KS(cur)[kbase + (((2 * st + hi) ^ ksw) << 3)];
        s = MFMA32(ka, qf[st], s);
      }
      __builtin_amdgcn_s_setprio(0);

      // ---- mask (diag only), max3-tree row max
      const bool nomask = (kb * 64 + 32 * hi2 + 31) <= (q0 + qg * 32);
      if (!nomask) {
#pragma unroll
        for (int i = 0; i < 16; ++i) {
          const int kr = kb * 64 + 32 * hi2 + (i & 3) + 8 * (i >> 2) + 4 * hi;
          s[i] = (kr <= qrow) ? s[i] : -INFINITY;
        }
      }
      float a0 = fmax3(s[0], s[1], s[2]);
      float a1 = fmax3(s[3], s[4], s[5]);
      float a2 = fmax3(s[6], s[7], s[8]);
      float a3 = fmax3(s[9], s[10], s[11]);
      float a4 = fmax3(s[12], s[13], s[14]);
      float b0 = fmax3(a0, a1, s[15]);
      float b1 = fmax3(a2, a3, a4);
      float pm = fmaxf(b0, b1);
      pm = fmaxf(pm, __shfl_xor(pm, 32));
      // ---- defer-max rescale
      if (!__all(pm <= m2 + 8.f)) {
        const float m2n = fmaxf(m2, pm);
        const float fc = exp2f(m2 - m2n);
        m2 = m2n; l *= fc;
#pragma unroll
        for (int dt = 0; dt < 4; ++dt)
#pragma unroll
          for (int i = 0; i < 16; ++i) o[dt][i] *= fc;
      }
      // ---- P = exp2(z - m2), tree local sum (cross-hi deferred)
#pragma unroll
      for (int i = 0; i < 16; ++i) s[i] = exp2f(s[i] - m2);
      float t8[8];
#pragma unroll
      for (int i = 0; i < 8; ++i) t8[i] = s[i] + s[i + 8];
#pragma unroll
      for (int i = 0; i < 4; ++i) t8[i] = t8[i] + t8[i + 4];
      l += (t8[0] + t8[1]) + (t8[2] + t8[3]);
      // ---- P C-regs -> B-operand directly (sigma order, perm pack)
      union PB { u32 wd[4]; bf16x8 v; } p0u, p1u;
#pragma unroll
      for (int q_ = 0; q_ < 4; ++q_) {
        p0u.wd[q_] = pk2(s[2 * q_],     s[2 * q_ + 1]);
        p1u.wd[q_] = pk2(s[8 + 2 * q_], s[8 + 2 * q_ + 1]);
      }
      // ---- O^T += V^T_half P_half  (rows d, cols q)
      __builtin_amdgcn_s_setprio(1);
#pragma unroll
      for (int dt = 0; dt < 4; ++dt) {
        const int vrow = (dt * 32 + l31) * 64;
        const int dsw = l31 & 7;
        bf16x8 va0 = *(const bf16x8*)&VT(cur)[vrow + (((4 * hi2 + hi) ^ dsw) << 3)];
        o[dt] = MFMA32(va0, p0u.v, o[dt]);
        bf16x8 va1 = *(const bf16x8*)&VT(cur)[vrow + (((4 * hi2 + 2 + hi) ^ dsw) << 3)];
        o[dt] = MFMA32(va1, p1u.v, o[dt]);
      }
      __builtin_amdgcn_s_setprio(0);
    }
  }

  // ---- in-LDS merge of the two k-halves (per tile x q-group slot)
  __syncthreads();                 // all compute done; SM reusable
  const float l_tot = l + __shfl_xor(l, 32);
  float* Mrg = (float*)SM;         // 16384 floats: [slot][dt][q=l31][32]
  float* Mlb = (float*)SM + 16384; // 256 floats: [slot][{m:0,l:32}+q]
  const int slot = (w >> 2) * 2 + qg;
  const int sw8 = l31 & 7;
  if (hi2) {
#pragma unroll
    for (int dt = 0; dt < 4; ++dt) {
      const int rbase = ((slot * 4 + dt) * 32 + l31) * 32;
#pragma unroll
      for (int m_ = 0; m_ < 4; ++m_) {
        f32x4 cv;
        cv[0] = o[dt][4 * m_ + 0]; cv[1] = o[dt][4 * m_ + 1];
        cv[2] = o[dt][4 * m_ + 2]; cv[3] = o[dt][4 * m_ + 3];
        *(f32x4*)&Mrg[rbase + (((hi * 4 + m_) ^ sw8) << 2)] = cv;
      }
    }
    if (hi == 0) {
      Mlb[slot * 64 + l31] = m2;
      Mlb[slot * 64 + 32 + l31] = l_tot;
    }
  }
  __syncthreads();
  if (!hi2) {
    const float m1 = Mlb[slot * 64 + l31];
    const float l1 = Mlb[slot * 64 + 32 + l31];
    const float ms = fmaxf(m2, m1);
    const float w0 = exp2f(m2 - ms), w1 = exp2f(m1 - ms);
    const float inv = 1.f / (w0 * l_tot + w1 * l1);
    const float aw0 = w0 * inv, aw1 = w1 * inv;
    const size_t orow = (size_t)(b * 2048 + qrow) * 2048 + h * 128;
#pragma unroll
    for (int dt = 0; dt < 4; ++dt) {
      const int rbase = ((slot * 4 + dt) * 32 + l31) * 32;
#pragma unroll
      for (int m_ = 0; m_ < 4; ++m_) {
        f32x4 o1v = *(const f32x4*)&Mrg[rbase + (((hi * 4 + m_) ^ sw8) << 2)];
        u64 val = 0;
#pragma unroll
        for (int r = 0; r < 4; ++r) {
          __hip_bfloat16 hb =
              __float2bfloat16(aw0 * o[dt][4 * m_ + r] + aw1 * o1v[r]);
          val |= (u64)(*(u16*)&hb) << (16 * r);
        }
        *(u64*)&ao[orow + dt * 32 + 8 * m_ + 4 * hi] = val;
      }
    }
  }
#undef STAGE_K
#undef STAGE_V
#undef KS
#undef VT
}

// ---------------------------------------------------------------- launch
extern "C" void kernel_launch(void* const* d_in, const int* in_sizes, int n_in,
                              void* d_out, int out_size, void* d_ws, size_t ws_size,
                              hipStream_t stream) {
  const float* x  = (const float*)d_in[0];
  const float* wq = (const float*)d_in[2];
  const float* wk = (const float*)d_in[3];
  const float* wv = (const float*)d_in[4];
  const float* wo = (const float*)d_in[5];
  float* out = (float*)d_out;

  u16* xb   = (u16*)d_ws;                       // x bf16   [4096][2048]
  u16* wqkv = xb + (size_t)8388608;             // W bf16   [3072][2048]
  u16* qkv  = wqkv + (size_t)6291456;           // qkv      [4096][3072]
  u16* vtg  = qkv + (size_t)12582912;           // V^T      [8][128][2048]
  u16* ao   = xb;                               // attn out [4096][2048] (reuse xb)
  u16* wob  = wqkv;                             // wo bf16  [2048][2048] (reuse)

  cast_f32_bf16<<<8192, 256, 0, stream>>>(x,  xb,   2097152);
  cast_f32_bf16<<<4096, 256, 0, stream>>>(wq, wqkv, 1048576);
  cast_f32_bf16<<<1024, 256, 0, stream>>>(wk, wqkv + (size_t)4194304, 262144);
  cast_f32_bf16<<<1024, 256, 0, stream>>>(wv, wqkv + (size_t)5242880, 262144);

  gemm_big<u16><<<dim3(12, 32), 512, 0, stream>>>(xb, wqkv, qkv, 4096, 3072, 2048);

  cast_f32_bf16<<<4096, 256, 0, stream>>>(wo, wob, 1048576);

  rmsrope_kernel<<<20480, 256, 0, stream>>>(qkv);
  vtrans_kernel<<<256, 256, 0, stream>>>(qkv, vtg);

  attn_kernel<<<512, 512, 0, stream>>>(qkv, vtg, ao);

  gemm_big<float><<<dim3(8, 32), 512, 0, stream>>>(ao, wob, out, 4096, 2048, 2048);
}

// Round 10
// 218.727 us; speedup vs baseline: 1.3063x; 1.0498x over previous
//
#include <hip/hip_runtime.h>
#include <hip/hip_bf16.h>

typedef unsigned short u16;
typedef unsigned int   u32;
typedef unsigned long long u64;
typedef __attribute__((ext_vector_type(8))) short bf16x8;
typedef __attribute__((ext_vector_type(4))) float f32x4;
typedef __attribute__((ext_vector_type(16))) float f32x16;

#define MFMA16(a,b,c) __builtin_amdgcn_mfma_f32_16x16x32_bf16((a),(b),(c),0,0,0)
#define MFMA32(a,b,c) __builtin_amdgcn_mfma_f32_32x32x16_bf16((a),(b),(c),0,0,0)

#define GLD16(gp, lp) __builtin_amdgcn_global_load_lds( \
    (const __attribute__((address_space(1))) void*)(gp), \
    (__attribute__((address_space(3))) void*)(lp), 16, 0, 0)

__device__ inline u32 pkbf(float a, float b) {
  __hip_bfloat16 ha = __float2bfloat16(a), hb = __float2bfloat16(b);
  return (u32)(*(u16*)&ha) | ((u32)(*(u16*)&hb) << 16);
}
__device__ inline float b2f(u16 x) {
  __hip_bfloat16 h; *(u16*)&h = x; return __bfloat162float(h);
}
// fast bf16 pair pack: round (+0x8000) then byte-perm the two high halves
__device__ inline u32 pk2(float a, float b) {
  u32 ua = __builtin_bit_cast(u32, a) + 0x8000u;
  u32 ub = __builtin_bit_cast(u32, b) + 0x8000u;
  return __builtin_amdgcn_perm(ub, ua, 0x07060302u);
}
__device__ inline float fmax3(float a, float b, float c) {
  return fmaxf(fmaxf(a, b), c);
}

// ---------------------------------------------------------------- cast f32->bf16
__global__ __launch_bounds__(256) void cast_f32_bf16(const float* __restrict__ src,
                                                     u16* __restrict__ dst, int n4) {
  int i = blockIdx.x * 256 + threadIdx.x;
  if (i >= n4) return;
  float4 v = reinterpret_cast<const float4*>(src)[i];
  uint2 pk; pk.x = pkbf(v.x, v.y); pk.y = pkbf(v.z, v.w);
  reinterpret_cast<uint2*>(dst)[i] = pk;
}

// ---------------------------------------------------------------- big GEMM
// C = A * B^T. Tile 128x256, BK=32, 512 thr = 8 waves (2M x 4N). Counted
// vmcnt(3) + raw s_barrier pipeline (no vmcnt(0) drain in main loop).
__device__ inline void cstore(u16* C, size_t i, float v) {
  __hip_bfloat16 h = __float2bfloat16(v); C[i] = *(u16*)&h;
}
__device__ inline void cstore(float* C, size_t i, float v) { C[i] = v; }

template<typename OutT>
__global__ __launch_bounds__(512, 4) void gemm_big(const u16* __restrict__ A,
                                                   const u16* __restrict__ B,
                                                   OutT* __restrict__ C,
                                                   int M, int N, int K) {
  __shared__ u16 As[2][128 * 32];   // 16K
  __shared__ u16 Bs[2][256 * 32];   // 32K

  const int t = threadIdx.x;
  const int lane = t & 63, wid = t >> 6;
  const int l15 = lane & 15, l4 = lane >> 4;
  const int wr = wid >> 2, wc = wid & 3;

  const int nwg = gridDim.x * gridDim.y;
  int lid = blockIdx.y * gridDim.x + blockIdx.x;
  lid = (lid & 7) * (nwg >> 3) + (lid >> 3);
  const int m0 = (lid / gridDim.x) * 128, n0 = (lid % gridDim.x) * 256;

  const int ra = t >> 2;
  const int ca = (t & 3) ^ ((ra >> 1) & 3);
  const u16* Ag  = A + (size_t)(m0 + ra) * K + ca * 8;
  const u16* Bg0 = B + (size_t)(n0 + ra) * K + ca * 8;
  const u16* Bg1 = B + (size_t)(n0 + 128 + ra) * K + ca * 8;

#define STAGE(k0_, buf_) do {                                                 \
    GLD16(Ag  + (k0_), &As[buf_][t * 8]);                                     \
    GLD16(Bg0 + (k0_), &Bs[buf_][t * 8]);                                     \
    GLD16(Bg1 + (k0_), &Bs[buf_][4096 + t * 8]);                              \
  } while (0)

  const int nk = K >> 5;
  const int ks = (l15 >> 1) & 3;
  const int coff = ((l4 ^ ks) << 3);

  f32x4 acc[4][4] = {};

  STAGE(0, 0);
  STAGE(32, 1);

  for (int j = 0; j < nk; ++j) {
    const int cur = j & 1;
    if (j + 1 < nk) asm volatile("s_waitcnt vmcnt(3)" ::: "memory");
    else            asm volatile("s_waitcnt vmcnt(0)" ::: "memory");
    __builtin_amdgcn_s_barrier();
    __builtin_amdgcn_sched_barrier(0);

    bf16x8 af[4], bfr[4];
#pragma unroll
    for (int mi = 0; mi < 4; ++mi)
      af[mi] = *(const bf16x8*)&As[cur][(wr * 64 + mi * 16 + l15) * 32 + coff];
#pragma unroll
    for (int ni = 0; ni < 4; ++ni)
      bfr[ni] = *(const bf16x8*)&Bs[cur][(wc * 64 + ni * 16 + l15) * 32 + coff];
    __builtin_amdgcn_s_setprio(1);
#pragma unroll
    for (int mi = 0; mi < 4; ++mi)
#pragma unroll
      for (int ni = 0; ni < 4; ++ni)
        acc[mi][ni] = MFMA16(af[mi], bfr[ni], acc[mi][ni]);
    __builtin_amdgcn_s_setprio(0);

    __builtin_amdgcn_s_barrier();
    if (j + 2 < nk) STAGE((j + 2) << 5, cur);
  }

  const int crow = m0 + wr * 64 + (l4 << 2);
  const int ccol = n0 + wc * 64 + l15;
#pragma unroll
  for (int mi = 0; mi < 4; ++mi)
#pragma unroll
    for (int ni = 0; ni < 4; ++ni)
#pragma unroll
      for (int r = 0; r < 4; ++r)
        cstore(C, (size_t)(crow + mi * 16 + r) * N + (ccol + ni * 16), acc[mi][ni][r]);
#undef STAGE
}

// ---------------------------------------------------------------- RMSNorm + RoPE
// q heads pre-scaled by (1/sqrt(128))*log2(e) -> QK^T lands in exp2 domain.
__global__ __launch_bounds__(256) void rmsrope_kernel(u16* __restrict__ qkv) {
  const int t = threadIdx.x;
  const int lane = t & 63;
  const int gw = blockIdx.x * 4 + (t >> 6);
  const int row = gw / 20;
  const int hd = gw - row * 20;
  const int col = (hd < 16) ? hd * 128 : 2048 + (hd - 16) * 128;
  const size_t base = (size_t)row * 3072 + col;
  float x1 = b2f(qkv[base + lane]);
  float x2 = b2f(qkv[base + 64 + lane]);
  float ss = x1 * x1 + x2 * x2;
#pragma unroll
  for (int off = 32; off >= 1; off >>= 1) ss += __shfl_xor(ss, off, 64);
  const float qsc = (hd < 16) ? (0.08838834764831845f * 1.44269504088896340f)
                              : 1.0f;
  const float sc = rsqrtf(ss * (1.0f / 128.0f) + 1e-6f) * qsc;
  const int pos = row & 2047;
  const float inv_freq = exp2f(-(float)lane * (13.287712379549449f / 64.0f));
  float sn, cs;
  sincosf((float)pos * inv_freq, &sn, &cs);
  const float a = x1 * sc, b2 = x2 * sc;
  __hip_bfloat16 o1 = __float2bfloat16(a * cs - b2 * sn);
  __hip_bfloat16 o2 = __float2bfloat16(a * sn + b2 * cs);
  qkv[base + lane] = *(u16*)&o1;
  qkv[base + 64 + lane] = *(u16*)&o2;
}

// ---------------------------------------------------------------- V transpose
// vt[g=b*4+kvh][d=128][s=2048], sigma-permuted s within each 64-group.
__global__ __launch_bounds__(256) void vtrans_kernel(const u16* __restrict__ qkv,
                                                     u16* __restrict__ vt) {
  __shared__ u16 Ls[64 * 130];
  const int t = threadIdx.x;
  const int g = blockIdx.x & 7, sb = blockIdx.x >> 3;
  const int b = g >> 2, kvh = g & 3;
  const int vcol = 2560 + kvh * 128;
  {
    const int row = t >> 4, dch = t & 15;
    const u16* src = qkv + (size_t)(b * 2048 + sb * 64 + row) * 3072 + vcol + dch * 8;
#pragma unroll
    for (int it = 0; it < 4; ++it) {
      bf16x8 v = *(const bf16x8*)(src + (size_t)it * 16 * 3072);
      *(bf16x8*)&Ls[(row + it * 16) * 130 + dch * 8] = v;
    }
  }
  __syncthreads();
  const int c = t & 7, d0 = t >> 3;
  const int k0 = 4 * (8 * (c >> 2) + 4 * ((c >> 1) & 1) + (c & 1));
#pragma unroll
  for (int it = 0; it < 4; ++it) {
    const int d = d0 + 32 * it;
    u16 v[8];
#pragma unroll
    for (int e = 0; e < 8; ++e)
      v[e] = Ls[(k0 + (e & 3) + 8 * (e >> 2)) * 130 + d];
    u64 lo = (u64)v[0] | ((u64)v[1] << 16) | ((u64)v[2] << 32) | ((u64)v[3] << 48);
    u64 hi = (u64)v[4] | ((u64)v[5] << 16) | ((u64)v[6] << 32) | ((u64)v[7] << 48);
    u64* dst = (u64*)(vt + ((size_t)g * 128 + d) * 2048 + sb * 64 + c * 8);
    dst[0] = lo; dst[1] = hi;
  }
}

// ---------------------------------------------------------------- flash attention
// r7 structure + T3/T4 counted-vmcnt schedule. 512 blocks x 256 thr = 4 waves
// (2 qg x 2 k-halves). Block = (g,h,j): q64-tile pair (j, 31-j) sequential =
// 33 KV iters (perfect balance); 2 blocks/CU. Main loop: s_waitcnt vmcnt(8)
// (batch kb done, batch kb+1's 8 GLDs stay in flight across barriers) ->
// s_barrier -> compute -> s_barrier -> stage batch kb+2. No vmcnt(0) drain
// except the last iter of each phase. Swapped QK^T (exp2-domain), zero-
// shuffle PV via sigma-ordered vt, XOR bank swizzles, defer-max.
__global__ __launch_bounds__(256, 2) void attn_kernel(const u16* __restrict__ qkv,
                                                      const u16* __restrict__ vt,
                                                      u16* __restrict__ ao) {
  __shared__ u16 Ks[2][64 * 128];   // [k][d], 16B chunks XORed by k&7 (32K)
  __shared__ u16 Vt[2][128 * 64];   // [d][sigma(k)], chunks XORed by d&7 (32K)

  const int t = threadIdx.x;
  const int lane = t & 63, w = t >> 6;
  const int l31 = lane & 31, hi = lane >> 5;
  const int qg = w >> 1, hi2 = w & 1;

  const int bid = blockIdx.x;
  const int g = bid & 7;                  // XCD group = (b, kvh)
  const int b = g >> 2, kvh = g & 3;
  const int idx = bid >> 3;
  const int h = kvh * 4 + (idx & 3);
  const int j = idx >> 2;                 // 0..15 -> pair (j, 31-j)

  const int kcol = 2048 + kvh * 128;
  const u16* vtg = vt + (size_t)g * 128 * 2048;

  const int krow_s = t >> 4, kchk = t & 15;   // K staging (4 GLD/thread)
  const int vd = t >> 3, vc = t & 7;          // V staging (4 GLD/thread)

#define STAGE_K(kb_, buf_) do {                                               \
    const size_t rb_ = (size_t)(b * 2048 + (kb_) * 64);                       \
    _Pragma("unroll")                                                         \
    for (int j_ = 0; j_ < 4; ++j_) {                                          \
      const int row_ = j_ * 16 + krow_s;                                      \
      GLD16(qkv + (rb_ + row_) * 3072 + kcol + ((kchk ^ (row_ & 7)) << 3),    \
            &Ks[buf_][(j_ * 256 + t) << 3]);                                  \
    } } while (0)

#define STAGE_V(kb_, buf_) do {                                               \
    _Pragma("unroll")                                                         \
    for (int j_ = 0; j_ < 4; ++j_) {                                          \
      const int d_ = j_ * 32 + vd;                                            \
      GLD16(vtg + (size_t)d_ * 2048 + (kb_) * 64 + ((vc ^ (d_ & 7)) << 3),    \
            &Vt[buf_][(j_ * 256 + t) << 3]);                                  \
    } } while (0)

  for (int ph = 0; ph < 2; ++ph) {
    const int qt64 = ph ? (31 - j) : j;
    const int q0 = qt64 * 64;
    const int nt = qt64 + 1;
    const int qrow = q0 + 32 * qg + l31;

    // Q fragments (B operand): col=q, k = st*16 + hi*8 + e (pre-scaled)
    bf16x8 qf[8];
    {
      const u16* qp = qkv + (size_t)(b * 2048 + qrow) * 3072 + h * 128 + hi * 8;
#pragma unroll
      for (int st = 0; st < 8; ++st) qf[st] = *(const bf16x8*)(qp + st * 16);
    }

    f32x16 o[4];
#pragma unroll
    for (int dt = 0; dt < 4; ++dt)
#pragma unroll
      for (int i = 0; i < 16; ++i) o[dt][i] = 0.f;
    float m2 = -1e30f, l = 0.f;

    // prologue: stage batches 0 and 1
    STAGE_K(0, 0);
    STAGE_V(0, 0);
    if (nt > 1) { STAGE_K(1, 1); STAGE_V(1, 1); }

    for (int kb = 0; kb < nt; ++kb) {
      const int cur = kb & 1;
      // wait for batch kb only; batch kb+1 (8 GLDs) stays in flight
      if (kb + 1 < nt) asm volatile("s_waitcnt vmcnt(8)" ::: "memory");
      else             asm volatile("s_waitcnt vmcnt(0)" ::: "memory");
      __builtin_amdgcn_s_barrier();
      __builtin_amdgcn_sched_barrier(0);

      // ---- S^T = K_half Q^T  (rows k of this wave's 32-half, cols q)
      f32x16 s;
#pragma unroll
      for (int i = 0; i < 16; ++i) s[i] = 0.f;
      const int kbase = (32 * hi2 + l31) * 128;
      const int ksw = l31 & 7;
      __builtin_amdgcn_s_setprio(1);
#pragma unroll
      for (int st = 0; st < 8; ++st) {
        bf16x8 ka = *(const bf16x8*)&Ks[cur][kbase + (((2 * st + hi) ^ ksw) << 3)];
        s = MFMA32(ka, qf[st], s);
      }
      __builtin_amdgcn_s_setprio(0);

      // ---- mask (diag only), max3-tree row max
      const bool nomask = (kb < qt64) || (hi2 == 0 && qg == 1);
      if (!nomask) {
#pragma unroll
        for (int i = 0; i < 16; ++i) {
          const int kr = kb * 64 + 32 * hi2 + (i & 3) + 8 * (i >> 2) + 4 * hi;
          s[i] = (kr <= qrow) ? s[i] : -INFINITY;
        }
      }
      float a0 = fmax3(s[0], s[1], s[2]);
      float a1 = fmax3(s[3], s[4], s[5]);
      float a2 = fmax3(s[6], s[7], s[8]);
      float a3 = fmax3(s[9], s[10], s[11]);
      float a4 = fmax3(s[12], s[13], s[14]);
      float b0 = fmax3(a0, a1, s[15]);
      float b1 = fmax3(a2, a3, a4);
      float pm = fmaxf(b0, b1);
      pm = fmaxf(pm, __shfl_xor(pm, 32));
      // ---- defer-max rescale
      if (!__all(pm <= m2 + 8.f)) {
        const float m2n = fmaxf(m2, pm);
        const float fc = exp2f(m2 - m2n);
        m2 = m2n; l *= fc;
#pragma unroll
        for (int dt = 0; dt < 4; ++dt)
#pragma unroll
          for (int i = 0; i < 16; ++i) o[dt][i] *= fc;
      }
      // ---- P = exp2(z - m2), tree local sum (cross-hi deferred)
#pragma unroll
      for (int i = 0; i < 16; ++i) s[i] = exp2f(s[i] - m2);
      float t8[8];
#pragma unroll
      for (int i = 0; i < 8; ++i) t8[i] = s[i] + s[i + 8];
#pragma unroll
      for (int i = 0; i < 4; ++i) t8[i] = t8[i] + t8[i + 4];
      l += (t8[0] + t8[1]) + (t8[2] + t8[3]);
      // ---- P C-regs -> B-operand directly (sigma order, perm pack)
      union PB { u32 wd[4]; bf16x8 v; } p0u, p1u;
#pragma unroll
      for (int q_ = 0; q_ < 4; ++q_) {
        p0u.wd[q_] = pk2(s[2 * q_],     s[2 * q_ + 1]);
        p1u.wd[q_] = pk2(s[8 + 2 * q_], s[8 + 2 * q_ + 1]);
      }
      // ---- O^T += V^T_half P_half  (rows d, cols q)
      __builtin_amdgcn_s_setprio(1);
#pragma unroll
      for (int dt = 0; dt < 4; ++dt) {
        const int vrow = (dt * 32 + l31) * 64;
        const int dsw = l31 & 7;
        bf16x8 va0 = *(const bf16x8*)&Vt[cur][vrow + (((4 * hi2 + hi) ^ dsw) << 3)];
        o[dt] = MFMA32(va0, p0u.v, o[dt]);
        bf16x8 va1 = *(const bf16x8*)&Vt[cur][vrow + (((4 * hi2 + 2 + hi) ^ dsw) << 3)];
        o[dt] = MFMA32(va1, p1u.v, o[dt]);
      }
      __builtin_amdgcn_s_setprio(0);

      __builtin_amdgcn_s_barrier();          // all waves done reading buf[cur]
      if (kb + 2 < nt) { STAGE_K(kb + 2, cur); STAGE_V(kb + 2, cur); }
    }

    // ---- in-block merge of the two k-halves (per q-group)
    __syncthreads();                 // all compute done; Ks/Vt reusable
    const float l_tot = l + __shfl_xor(l, 32);
    float* Mrg = (float*)&Ks[0][0];
    float* Mlb = (float*)&Vt[0][0];
    const int sw8 = l31 & 7;
    if (hi2) {
#pragma unroll
      for (int dt = 0; dt < 4; ++dt) {
        const int rbase = ((qg * 4 + dt) * 32 + l31) * 32;
#pragma unroll
        for (int m_ = 0; m_ < 4; ++m_) {
          f32x4 cv;
          cv[0] = o[dt][4 * m_ + 0]; cv[1] = o[dt][4 * m_ + 1];
          cv[2] = o[dt][4 * m_ + 2]; cv[3] = o[dt][4 * m_ + 3];
          *(f32x4*)&Mrg[rbase + (((hi * 4 + m_) ^ sw8) << 2)] = cv;
        }
      }
      if (hi == 0) {
        Mlb[qg * 64 + l31] = m2;
        Mlb[qg * 64 + 32 + l31] = l_tot;
      }
    }
    __syncthreads();
    if (!hi2) {
      const float m1 = Mlb[qg * 64 + l31];
      const float l1 = Mlb[qg * 64 + 32 + l31];
      const float ms = fmaxf(m2, m1);
      const float w0 = exp2f(m2 - ms), w1 = exp2f(m1 - ms);
      const float inv = 1.f / (w0 * l_tot + w1 * l1);
      const float aw0 = w0 * inv, aw1 = w1 * inv;
      const size_t orow = (size_t)(b * 2048 + qrow) * 2048 + h * 128;
#pragma unroll
      for (int dt = 0; dt < 4; ++dt) {
        const int rbase = ((qg * 4 + dt) * 32 + l31) * 32;
#pragma unroll
        for (int m_ = 0; m_ < 4; ++m_) {
          f32x4 o1v = *(const f32x4*)&Mrg[rbase + (((hi * 4 + m_) ^ sw8) << 2)];
          u64 val = 0;
#pragma unroll
          for (int r = 0; r < 4; ++r) {
            __hip_bfloat16 hb =
                __float2bfloat16(aw0 * o[dt][4 * m_ + r] + aw1 * o1v[r]);
            val |= (u64)(*(u16*)&hb) << (16 * r);
          }
          *(u64*)&ao[orow + dt * 32 + 8 * m_ + 4 * hi] = val;
        }
      }
    }
    __syncthreads();                 // protect Mrg/Mlb before next-phase staging
  }
#undef STAGE_K
#undef STAGE_V
}

// ---------------------------------------------------------------- launch
extern "C" void kernel_launch(void* const* d_in, const int* in_sizes, int n_in,
                              void* d_out, int out_size, void* d_ws, size_t ws_size,
                              hipStream_t stream) {
  const float* x  = (const float*)d_in[0];
  const float* wq = (const float*)d_in[2];
  const float* wk = (const float*)d_in[3];
  const float* wv = (const float*)d_in[4];
  const float* wo = (const float*)d_in[5];
  float* out = (float*)d_out;

  u16* xb   = (u16*)d_ws;                       // x bf16   [4096][2048]
  u16* wqkv = xb + (size_t)8388608;             // W bf16   [3072][2048]
  u16* qkv  = wqkv + (size_t)6291456;           // qkv      [4096][3072]
  u16* vtg  = qkv + (size_t)12582912;           // V^T      [8][128][2048]
  u16* ao   = xb;                               // attn out [4096][2048] (reuse xb)
  u16* wob  = wqkv;                             // wo bf16  [2048][2048] (reuse)

  cast_f32_bf16<<<8192, 256, 0, stream>>>(x,  xb,   2097152);
  cast_f32_bf16<<<4096, 256, 0, stream>>>(wq, wqkv, 1048576);
  cast_f32_bf16<<<1024, 256, 0, stream>>>(wk, wqkv + (size_t)4194304, 262144);
  cast_f32_bf16<<<1024, 256, 0, stream>>>(wv, wqkv + (size_t)5242880, 262144);

  gemm_big<u16><<<dim3(12, 32), 512, 0, stream>>>(xb, wqkv, qkv, 4096, 3072, 2048);

  cast_f32_bf16<<<4096, 256, 0, stream>>>(wo, wob, 1048576);

  rmsrope_kernel<<<20480, 256, 0, stream>>>(qkv);
  vtrans_kernel<<<256, 256, 0, stream>>>(qkv, vtg);

  attn_kernel<<<512, 256, 0, stream>>>(qkv, vtg, ao);

  gemm_big<float><<<dim3(8, 32), 512, 0, stream>>>(ao, wob, out, 4096, 2048, 2048);
}